// Round 1
// baseline (265.977 us; speedup 1.0000x reference)
//
#include <hip/hip_runtime.h>
#include <float.h>

#define N_SRC 20000
#define N_TAR 20000
#define TPB 256
#define SC 10                       // source chunks (grid.y)
#define CHUNK (N_SRC / SC)          // 2000 sources per chunk, 32 KB LDS
#define TBLOCKS ((N_TAR + TPB - 1) / TPB)   // 79

// Stage 1: for each (target, source-chunk) compute partial min of
// q = 0.5*||s||^2 - t.s   (so that d2 = ||t||^2 + 2q)
__global__ __launch_bounds__(TPB) void nn_partial_min(
    const float* __restrict__ src, const float* __restrict__ tar,
    float* __restrict__ part)
{
    __shared__ float4 sh[CHUNK];
    const int c = blockIdx.y;
    const int base = c * CHUNK;
    for (int i = threadIdx.x; i < CHUNK; i += TPB) {
        const float x = src[(base + i) * 3 + 0];
        const float y = src[(base + i) * 3 + 1];
        const float z = src[(base + i) * 3 + 2];
        sh[i] = make_float4(x, y, z, 0.5f * (x * x + y * y + z * z));
    }
    __syncthreads();

    const int t = blockIdx.x * TPB + threadIdx.x;
    float ntx = 0.f, nty = 0.f, ntz = 0.f;
    if (t < N_TAR) {
        ntx = -tar[t * 3 + 0];
        nty = -tar[t * 3 + 1];
        ntz = -tar[t * 3 + 2];
    }
    float m = FLT_MAX;
    // inner loop: 1 broadcast ds_read_b128 + 3 v_fma + 1 v_min per source
#pragma unroll 8
    for (int i = 0; i < CHUNK; ++i) {
        const float4 p = sh[i];
        const float q = fmaf(ntx, p.x, fmaf(nty, p.y, fmaf(ntz, p.z, p.w)));
        m = fminf(m, q);
    }
    if (t < N_TAR) part[c * N_TAR + t] = m;
}

// Stage 2: combine chunk mins, add 0.5*||t||^2, reduce-sum into out[0].
__global__ __launch_bounds__(TPB) void nn_finalize(
    const float* __restrict__ tar, const float* __restrict__ part,
    float* __restrict__ out)
{
    const int t = blockIdx.x * TPB + threadIdx.x;
    float contrib = 0.f;
    if (t < N_TAR) {
        float m = FLT_MAX;
#pragma unroll
        for (int c = 0; c < SC; ++c) m = fminf(m, part[c * N_TAR + t]);
        const float tx = tar[t * 3 + 0];
        const float ty = tar[t * 3 + 1];
        const float tz = tar[t * 3 + 2];
        // 0.5 * d2_min = 0.5*||t||^2 + m
        contrib = 0.5f * (tx * tx + ty * ty + tz * tz) + m;
    }
    // wave(64)-level shuffle reduction
    for (int off = 32; off > 0; off >>= 1)
        contrib += __shfl_down(contrib, off);
    __shared__ float red[TPB / 64];
    const int wave = threadIdx.x >> 6;
    const int lane = threadIdx.x & 63;
    if (lane == 0) red[wave] = contrib;
    __syncthreads();
    if (threadIdx.x == 0) {
        float s = 0.f;
#pragma unroll
        for (int w = 0; w < TPB / 64; ++w) s += red[w];
        atomicAdd(out, s);
    }
}

extern "C" void kernel_launch(void* const* d_in, const int* in_sizes, int n_in,
                              void* d_out, int out_size, void* d_ws, size_t ws_size,
                              hipStream_t stream) {
    const float* src = (const float*)d_in[0];  // src_V [20000,3] fp32
    const float* tar = (const float*)d_in[1];  // tar_V [20000,3] fp32
    float* out = (float*)d_out;                // scalar fp32
    float* part = (float*)d_ws;                // SC * N_TAR floats = 800 KB

    hipMemsetAsync(out, 0, sizeof(float), stream);  // d_out is poisoned 0xAA

    dim3 grid1(TBLOCKS, SC);
    nn_partial_min<<<grid1, TPB, 0, stream>>>(src, tar, part);
    nn_finalize<<<TBLOCKS, TPB, 0, stream>>>(tar, part, out);
}

// Round 2
// 126.356 us; speedup vs baseline: 2.1050x; 2.1050x over previous
//
#include <hip/hip_runtime.h>
#include <float.h>

#define N_SRC 20000
#define N_TAR 20000
#define TPB 256
#define T 16                      // targets per thread (register tile)
#define TGT_PER_BLK (TPB * T)     // 4096
#define TBLK 5                    // ceil(20000 / 4096)
#define SC 102                    // source chunks
#define CHUNK 197                 // ceil(20000 / 102)
#define FBLOCKS ((N_TAR + TPB - 1) / TPB)   // 79

// order-preserving float -> uint key (for atomicMin fallback path)
__device__ __forceinline__ unsigned enc(float f) {
    unsigned u = __float_as_uint(f);
    return (u & 0x80000000u) ? ~u : (u | 0x80000000u);
}
__device__ __forceinline__ float dec(unsigned k) {
    unsigned u = (k & 0x80000000u) ? (k ^ 0x80000000u) : ~k;
    return __uint_as_float(u);
}

// Stage 1: per (target-block, source-chunk), each thread keeps T targets in
// registers; one broadcast ds_read_b128 per source feeds T*(3 fma + 1 min).
// q = 0.5*||s||^2 - t.s  so that 0.5*d2 = 0.5*||t||^2 + q
template <bool ATOMIC>
__global__ __launch_bounds__(TPB) void nn_partial_min(
    const float* __restrict__ src, const float* __restrict__ tar,
    float* __restrict__ part, unsigned* __restrict__ keys)
{
    __shared__ float4 sh[CHUNK];
    const int c = blockIdx.y;
    const int base = c * CHUNK;
    for (int i = threadIdx.x; i < CHUNK; i += TPB) {
        const int s = base + i;
        if (s < N_SRC) {
            const float x = src[s * 3 + 0];
            const float y = src[s * 3 + 1];
            const float z = src[s * 3 + 2];
            sh[i] = make_float4(x, y, z, 0.5f * (x * x + y * y + z * z));
        } else {
            sh[i] = make_float4(0.f, 0.f, 0.f, 3e38f);  // never the min
        }
    }
    __syncthreads();

    const int t0 = blockIdx.x * TGT_PER_BLK + threadIdx.x;
    float ntx[T], nty[T], ntz[T], m[T];
#pragma unroll
    for (int j = 0; j < T; ++j) {
        const int t = t0 + j * TPB;
        const bool v = t < N_TAR;
        const int ti = v ? t : 0;
        ntx[j] = v ? -tar[ti * 3 + 0] : 0.f;
        nty[j] = v ? -tar[ti * 3 + 1] : 0.f;
        ntz[j] = v ? -tar[ti * 3 + 2] : 0.f;
        m[j] = FLT_MAX;
    }

    for (int i = 0; i < CHUNK; ++i) {
        const float4 p = sh[i];
#pragma unroll
        for (int j = 0; j < T; ++j) {
            const float q = fmaf(ntx[j], p.x,
                            fmaf(nty[j], p.y,
                            fmaf(ntz[j], p.z, p.w)));
            m[j] = fminf(m[j], q);
        }
    }

#pragma unroll
    for (int j = 0; j < T; ++j) {
        const int t = t0 + j * TPB;
        if (t < N_TAR) {
            if (ATOMIC) atomicMin(&keys[t], enc(m[j]));
            else        part[c * N_TAR + t] = m[j];
        }
    }
}

__device__ __forceinline__ void reduce_and_add(float contrib, float* out) {
    for (int off = 32; off > 0; off >>= 1)
        contrib += __shfl_down(contrib, off);
    __shared__ float red[TPB / 64];
    const int wave = threadIdx.x >> 6;
    const int lane = threadIdx.x & 63;
    if (lane == 0) red[wave] = contrib;
    __syncthreads();
    if (threadIdx.x == 0) {
        float s = 0.f;
#pragma unroll
        for (int w = 0; w < TPB / 64; ++w) s += red[w];
        atomicAdd(out, s);
    }
}

__global__ __launch_bounds__(TPB) void nn_finalize_part(
    const float* __restrict__ tar, const float* __restrict__ part,
    float* __restrict__ out)
{
    const int t = blockIdx.x * TPB + threadIdx.x;
    float contrib = 0.f;
    if (t < N_TAR) {
        float m = FLT_MAX;
        for (int c = 0; c < SC; ++c) m = fminf(m, part[c * N_TAR + t]);
        const float tx = tar[t * 3 + 0];
        const float ty = tar[t * 3 + 1];
        const float tz = tar[t * 3 + 2];
        contrib = 0.5f * (tx * tx + ty * ty + tz * tz) + m;
    }
    reduce_and_add(contrib, out);
}

__global__ __launch_bounds__(TPB) void nn_finalize_atomic(
    const float* __restrict__ tar, const unsigned* __restrict__ keys,
    float* __restrict__ out)
{
    const int t = blockIdx.x * TPB + threadIdx.x;
    float contrib = 0.f;
    if (t < N_TAR) {
        const float m = dec(keys[t]);
        const float tx = tar[t * 3 + 0];
        const float ty = tar[t * 3 + 1];
        const float tz = tar[t * 3 + 2];
        contrib = 0.5f * (tx * tx + ty * ty + tz * tz) + m;
    }
    reduce_and_add(contrib, out);
}

extern "C" void kernel_launch(void* const* d_in, const int* in_sizes, int n_in,
                              void* d_out, int out_size, void* d_ws, size_t ws_size,
                              hipStream_t stream) {
    const float* src = (const float*)d_in[0];  // [20000,3] fp32
    const float* tar = (const float*)d_in[1];  // [20000,3] fp32
    float* out = (float*)d_out;

    hipMemsetAsync(out, 0, sizeof(float), stream);

    const size_t part_bytes = (size_t)SC * N_TAR * sizeof(float);  // ~8.2 MB
    const dim3 grid1(TBLK, SC);

    if (ws_size >= part_bytes) {
        float* part = (float*)d_ws;
        nn_partial_min<false><<<grid1, TPB, 0, stream>>>(src, tar, part, nullptr);
        nn_finalize_part<<<FBLOCKS, TPB, 0, stream>>>(tar, part, out);
    } else {
        unsigned* keys = (unsigned*)d_ws;      // 80 KB
        hipMemsetAsync(keys, 0xFF, (size_t)N_TAR * sizeof(unsigned), stream);
        nn_partial_min<true><<<grid1, TPB, 0, stream>>>(src, tar, nullptr, keys);
        nn_finalize_atomic<<<FBLOCKS, TPB, 0, stream>>>(tar, keys, out);
    }
}